// Round 3
// 1221.592 us; speedup vs baseline: 1.0162x; 1.0162x over previous
//
#include <hip/hip_runtime.h>
#include <stdint.h>

typedef unsigned short u16;
typedef short bf16x8 __attribute__((ext_vector_type(8)));
typedef float floatx4 __attribute__((ext_vector_type(4)));

__device__ __forceinline__ u16 f2b(float f) {
  union { float f; unsigned u; } v; v.f = f;
  return (u16)((v.u + 0x7FFFu + ((v.u >> 16) & 1u)) >> 16);
}
__device__ __forceinline__ float b2f(u16 u) {
  union { float f; unsigned u; } v; v.u = ((unsigned)u) << 16; return v.f;
}
__device__ __forceinline__ void gload_lds16(const void* g, void* l) {
  __builtin_amdgcn_global_load_lds((const __attribute__((address_space(1))) void*)g,
                                   (__attribute__((address_space(3))) void*)l, 16, 0, 0);
}

// img_feats (N,8,3200) fp32 -> A_bf (N*3, 3200) bf16, keeping s=0..2 only
__global__ void k_convert_A(const float* __restrict__ img, u16* __restrict__ out) {
  int row = blockIdx.x;            // 0..3N-1
  int n = row / 3, s = row - n * 3;
  const float* src = img + (size_t)(n * 8 + s) * 3200;
  u16* dst = out + (size_t)row * 3200;
  for (int c = threadIdx.x; c < 800; c += 256) {
    float4 v = ((const float4*)src)[c];
    ushort4 o = {f2b(v.x), f2b(v.y), f2b(v.z), f2b(v.w)};
    ((ushort4*)dst)[c] = o;
  }
}

// LDS-tiled transpose: in (batch,R,C) fp32 -> out (batch,C,R) bf16. 32x32 tiles.
__global__ void k_transpose_tile(const float* __restrict__ in, u16* __restrict__ out,
                                 int R, int C) {
  __shared__ float t[32][33];
  int a = blockIdx.z;
  const float* src = in + (size_t)a * R * C;
  u16* dst = out + (size_t)a * R * C;
  int rb = blockIdx.x << 5, cb = blockIdx.y << 5;
  int tx = threadIdx.x & 31, ty = threadIdx.x >> 5;   // 32 x 8
#pragma unroll
  for (int i = 0; i < 32; i += 8)
    t[ty + i][tx] = src[(size_t)(rb + ty + i) * C + cb + tx];
  __syncthreads();
#pragma unroll
  for (int i = 0; i < 32; i += 8)
    dst[(size_t)(cb + ty + i) * R + rb + tx] = f2b(t[tx][ty + i]);
}

// bucket samples by attr; buckets padded to multiple of 128 rows.
// Wave-aggregated counting/scatter: uniform-address atomics only (G12).
__global__ void k_bucket(const int* __restrict__ attrs, int N, int maxTiles,
                         int* __restrict__ perm, int* __restrict__ tattr) {
  __shared__ int cnt[8], off[8], cur[8];
  int tid = threadIdx.x;
  int nt = blockDim.x;
  int lane = tid & 63;
  if (tid < 8) cnt[tid] = 0;
  __syncthreads();
  for (int n0 = 0; n0 < N; n0 += nt) {
    int n = n0 + tid;
    int a = (n < N) ? attrs[n] : -1;
#pragma unroll
    for (int b = 0; b < 7; b++) {
      unsigned long long m = __ballot(a == b);
      if (m && lane == 0) atomicAdd(&cnt[b], __popcll(m));
    }
  }
  __syncthreads();
  if (tid == 0) {
    int o = 0;
    for (int a = 0; a < 7; a++) { off[a] = o; cur[a] = o; o += ((cnt[a] + 127) >> 7) << 7; }
    off[7] = o;
  }
  __syncthreads();
  int Mpad = maxTiles << 7;
  for (int i = tid; i < Mpad; i += nt) perm[i] = -1;
  for (int t = tid; t < maxTiles; t += nt) {
    int row = t << 7;
    int a = 0;
    for (int b = 1; b < 7; b++) if (row >= off[b]) a = b;
    tattr[t] = (row < off[7]) ? a : 0;
  }
  __syncthreads();
  for (int n0 = 0; n0 < N; n0 += nt) {
    int n = n0 + tid;
    int a = (n < N) ? attrs[n] : -1;
#pragma unroll
    for (int b = 0; b < 7; b++) {
      unsigned long long m = __ballot(a == b);
      if (m) {
        int lead = __ffsll(m) - 1;
        int base = 0;
        if (lane == lead) base = atomicAdd(&cur[b], __popcll(m));
        base = __shfl(base, lead, 64);
        if (a == b) {
          int pre = __popcll(m & ((1ull << lane) - 1ull));
          perm[base + pre] = n;
        }
      }
    }
  }
}

// x_sorted (Mpad,1024) bf16: plain=[f0,f1] or prod=[f0*f1, f1*f2]
__global__ void k_build_x(const int* __restrict__ perm, const int* __restrict__ attrs,
                          const u16* __restrict__ feats, u16* __restrict__ x) {
  int row = blockIdx.x;
  int c0 = threadIdx.x << 2;
  u16* xr = x + (size_t)row * 1024;
  int n = perm[row];
  if (n < 0) { ushort4 z = {0, 0, 0, 0}; *(ushort4*)&xr[c0] = z; return; }
  int attr = attrs[n];
  bool dist = (attr == 5) || (attr == 6);
  const u16* fb = feats + (size_t)(n * 3) * 512;
  ushort4 o;
  if (c0 < 512) {
    ushort4 a = *(const ushort4*)&fb[c0];            // f0
    if (dist) {
      ushort4 b = *(const ushort4*)&fb[512 + c0];    // f1
      o.x = f2b(b2f(a.x) * b2f(b.x)); o.y = f2b(b2f(a.y) * b2f(b.y));
      o.z = f2b(b2f(a.z) * b2f(b.z)); o.w = f2b(b2f(a.w) * b2f(b.w));
    } else o = a;
  } else {
    int c = c0 - 512;
    ushort4 a = *(const ushort4*)&fb[512 + c];       // f1
    if (dist) {
      ushort4 b = *(const ushort4*)&fb[1024 + c];    // f2
      o.x = f2b(b2f(a.x) * b2f(b.x)); o.y = f2b(b2f(a.y) * b2f(b.y));
      o.z = f2b(b2f(a.z) * b2f(b.z)); o.w = f2b(b2f(a.w) * b2f(b.w));
    } else o = a;
  }
  *(ushort4*)&xr[c0] = o;
}

// C(M,512) = relu(A(M,K) * Bt(512,K)^T + bias), bf16 out. 128x128 tile, BK=64.
// Grid: (bmTilesPadded, 4). bm on x so same-A blocks (ids bm + gridX*bn) land on
// the same XCD when gridX % 8 == 0 -> A-tile is 1-miss-3-hit in that XCD's L2.
__global__ __launch_bounds__(256) void k_gemm_bt(
    const u16* __restrict__ A, const u16* __restrict__ Bt,
    const float* __restrict__ bias, u16* __restrict__ C,
    int K, const int* __restrict__ tattr, int bStride, int biasStride, int mTiles) {
  __shared__ u16 sA[128 * 64];
  __shared__ u16 sB[128 * 64];
  int tid = threadIdx.x;
  int bm = blockIdx.x, bn = blockIdx.y;
  if (bm >= mTiles) return;   // uniform per block: safe w.r.t. barriers
  int attr = tattr ? tattr[bm] : 0;
  const u16* Ab = A + (size_t)bm * 128 * K;
  const u16* Bb = Bt + (size_t)attr * bStride + (size_t)bn * 128 * K;
  int lane = tid & 63, wave = tid >> 6;
  int wm = (wave >> 1) * 64, wn = (wave & 1) * 64;
  int lr = lane & 15, lq = lane >> 4;
  floatx4 acc[4][4];
#pragma unroll
  for (int i = 0; i < 4; i++)
#pragma unroll
    for (int j = 0; j < 4; j++) acc[i][j] = floatx4{0.f, 0.f, 0.f, 0.f};
  int r = tid >> 3;            // 0..31
  int c8 = (tid & 7) << 3;     // 0..56
  int iters = K >> 6;
  for (int kk = 0; kk < iters; kk++) {
    int k0 = kk << 6;
    const u16* Abk = Ab + k0 + c8;
    const u16* Bbk = Bb + k0 + c8;
#pragma unroll
    for (int i = 0; i < 4; i++) {
      gload_lds16(Abk + (size_t)(r + i * 32) * K, &sA[(size_t)(tid + i * 256) << 3]);
      gload_lds16(Bbk + (size_t)(r + i * 32) * K, &sB[(size_t)(tid + i * 256) << 3]);
    }
    __syncthreads();
#pragma unroll
    for (int ks = 0; ks < 2; ks++) {
      int kb = (ks << 5) + (lq << 3);
      bf16x8 af[4], bg[4];
#pragma unroll
      for (int i = 0; i < 4; i++) {
        af[i] = *(const bf16x8*)&sA[(wm + i * 16 + lr) * 64 + kb];
        bg[i] = *(const bf16x8*)&sB[(wn + i * 16 + lr) * 64 + kb];
      }
#pragma unroll
      for (int i = 0; i < 4; i++)
#pragma unroll
        for (int j = 0; j < 4; j++)
          acc[i][j] = __builtin_amdgcn_mfma_f32_16x16x32_bf16(af[i], bg[j], acc[i][j], 0, 0, 0);
    }
    __syncthreads();
  }
  // epilogue: C/D layout col=lane&15, row=quad*4+reg (m89/m91-verified)
  const float* br = bias + attr * biasStride;
  int colBase = bn * 128 + wn + lr;
  int rowBase = bm * 128 + wm + lq * 4;
#pragma unroll
  for (int i = 0; i < 4; i++) {
#pragma unroll
    for (int j = 0; j < 4; j++) {
      int col = colBase + j * 16;
      float bv = br[col];
#pragma unroll
      for (int r4 = 0; r4 < 4; r4++) {
        int row = rowBase + i * 16 + r4;
        float v = fmaxf(acc[i][j][r4] + bv, 0.f);
        C[(size_t)row * 512 + col] = f2b(v);
      }
    }
  }
}

// scores[n,0:2] = h[row]·W2[attr] + b2[attr], fp32, scatter via perm
__global__ void k_layer3(const int* __restrict__ perm, const int* __restrict__ attrs,
                         const u16* __restrict__ h, const float* __restrict__ W2,
                         const float* __restrict__ b2, float* __restrict__ out) {
  int row = blockIdx.x * 4 + (threadIdx.x >> 6);
  int lane = threadIdx.x & 63;
  int n = perm[row];
  if (n < 0) return;
  int attr = attrs[n];
  const u16* hp = h + (size_t)row * 512 + lane * 8;
  uint4 hv = *(const uint4*)hp;
  float hf[8];
  hf[0] = b2f((u16)(hv.x & 0xFFFF)); hf[1] = b2f((u16)(hv.x >> 16));
  hf[2] = b2f((u16)(hv.y & 0xFFFF)); hf[3] = b2f((u16)(hv.y >> 16));
  hf[4] = b2f((u16)(hv.z & 0xFFFF)); hf[5] = b2f((u16)(hv.z >> 16));
  hf[6] = b2f((u16)(hv.w & 0xFFFF)); hf[7] = b2f((u16)(hv.w >> 16));
  const float* w = W2 + attr * 1024 + lane * 16;   // (f*2+a), f=lane*8..+7
  float a0 = 0.f, a1 = 0.f;
#pragma unroll
  for (int j = 0; j < 8; j++) { a0 += hf[j] * w[2 * j]; a1 += hf[j] * w[2 * j + 1]; }
#pragma unroll
  for (int m = 32; m; m >>= 1) { a0 += __shfl_xor(a0, m, 64); a1 += __shfl_xor(a1, m, 64); }
  if (lane == 0) {
    out[(size_t)n * 2 + 0] = a0 + b2[attr * 2 + 0];
    out[(size_t)n * 2 + 1] = a1 + b2[attr * 2 + 1];
  }
}

extern "C" void kernel_launch(void* const* d_in, const int* in_sizes, int n_in,
                              void* d_out, int out_size, void* d_ws, size_t ws_size,
                              hipStream_t stream) {
  const float* img   = (const float*)d_in[0];
  const int*   attrs = (const int*)d_in[1];
  const float* Wcnn  = (const float*)d_in[2];
  const float* bcnn  = (const float*)d_in[3];
  const float* W1    = (const float*)d_in[4];
  const float* b1    = (const float*)d_in[5];
  const float* W2    = (const float*)d_in[6];
  const float* b2    = (const float*)d_in[7];
  float* out = (float*)d_out;

  int N = in_sizes[1];          // 8192
  int M1 = N * 3;               // 24576 rows for layer-1 GEMM
  int mtiles1 = M1 / 128;       // 192 (multiple of 8 -> XCD-aligned swizzle)
  int maxTiles = N / 128 + 7;   // 71 (worst-case padded bucket tiles)
  int mtiles2p = (maxTiles + 7) & ~7;  // 72, pad so gridX % 8 == 0
  int Mpad = maxTiles * 128;    // 9088

  char* ws = (char*)d_ws;
  size_t off = 0;
  auto alloc = [&](size_t b) { char* p = ws + off; off += (b + 255) & ~(size_t)255; return p; };
  u16* A_bf  = (u16*)alloc((size_t)M1 * 3200 * 2);       // 157 MB
  u16* Wt    = (u16*)alloc((size_t)512 * 3200 * 2);      // 3.3 MB  (W_cnn^T)
  u16* W1t   = (u16*)alloc((size_t)7 * 512 * 1024 * 2);  // 7.3 MB  (W1^T per attr)
  u16* feats = (u16*)alloc((size_t)M1 * 512 * 2);        // 25 MB
  u16* xs    = (u16*)alloc((size_t)Mpad * 1024 * 2);     // 18.6 MB
  u16* hs    = (u16*)alloc((size_t)Mpad * 512 * 2);      // 9.3 MB
  int* perm  = (int*)alloc((size_t)Mpad * 4);
  int* tattr = (int*)alloc((size_t)maxTiles * 4);

  hipLaunchKernelGGL(k_convert_A, dim3(M1), dim3(256), 0, stream, img, A_bf);
  hipLaunchKernelGGL(k_transpose_tile, dim3(3200 / 32, 512 / 32, 1), dim3(256), 0, stream,
                     Wcnn, Wt, 3200, 512);
  hipLaunchKernelGGL(k_transpose_tile, dim3(1024 / 32, 512 / 32, 7), dim3(256), 0, stream,
                     W1, W1t, 1024, 512);
  hipLaunchKernelGGL(k_bucket, dim3(1), dim3(1024), 0, stream, attrs, N, maxTiles, perm, tattr);
  hipLaunchKernelGGL(k_gemm_bt, dim3(mtiles1, 4), dim3(256), 0, stream,
                     A_bf, Wt, bcnn, feats, 3200, (const int*)nullptr, 0, 0, mtiles1);
  hipLaunchKernelGGL(k_build_x, dim3(Mpad), dim3(256), 0, stream, perm, attrs, feats, xs);
  hipLaunchKernelGGL(k_gemm_bt, dim3(mtiles2p, 4), dim3(256), 0, stream,
                     xs, W1t, b1, hs, 1024, tattr, 512 * 1024, 512, maxTiles);
  hipLaunchKernelGGL(k_layer3, dim3(Mpad / 4), dim3(256), 0, stream, perm, attrs, hs, W2, b2, out);
}

// Round 4
// 1209.713 us; speedup vs baseline: 1.0262x; 1.0098x over previous
//
#include <hip/hip_runtime.h>
#include <stdint.h>

typedef unsigned short u16;
typedef short bf16x8 __attribute__((ext_vector_type(8)));
typedef float floatx4 __attribute__((ext_vector_type(4)));

__device__ __forceinline__ u16 f2b(float f) {
  union { float f; unsigned u; } v; v.f = f;
  return (u16)((v.u + 0x7FFFu + ((v.u >> 16) & 1u)) >> 16);
}
__device__ __forceinline__ float b2f(u16 u) {
  union { float f; unsigned u; } v; v.u = ((unsigned)u) << 16; return v.f;
}
// pack two fp32 -> one u32 holding (bf16(lo) | bf16(hi)<<16), RNE
__device__ __forceinline__ unsigned pk2(float lo, float hi) {
  return (unsigned)f2b(lo) | ((unsigned)f2b(hi) << 16);
}
__device__ __forceinline__ void gload_lds16(const void* g, void* l) {
  __builtin_amdgcn_global_load_lds((const __attribute__((address_space(1))) void*)g,
                                   (__attribute__((address_space(3))) void*)l, 16, 0, 0);
}

// LDS-tiled transpose: in (batch,R,C) fp32 -> out (batch,C,R) bf16. 32x32 tiles.
__global__ void k_transpose_tile(const float* __restrict__ in, u16* __restrict__ out,
                                 int R, int C) {
  __shared__ float t[32][33];
  int a = blockIdx.z;
  const float* src = in + (size_t)a * R * C;
  u16* dst = out + (size_t)a * R * C;
  int rb = blockIdx.x << 5, cb = blockIdx.y << 5;
  int tx = threadIdx.x & 31, ty = threadIdx.x >> 5;   // 32 x 8
#pragma unroll
  for (int i = 0; i < 32; i += 8)
    t[ty + i][tx] = src[(size_t)(rb + ty + i) * C + cb + tx];
  __syncthreads();
#pragma unroll
  for (int i = 0; i < 32; i += 8)
    dst[(size_t)(cb + ty + i) * R + rb + tx] = f2b(t[tx][ty + i]);
}

// bucket samples by attr; buckets padded to multiple of 128 rows.
// Wave-aggregated counting/scatter: uniform-address atomics only (G12).
__global__ void k_bucket(const int* __restrict__ attrs, int N, int maxTiles,
                         int* __restrict__ perm, int* __restrict__ tattr) {
  __shared__ int cnt[8], off[8], cur[8];
  int tid = threadIdx.x;
  int nt = blockDim.x;
  int lane = tid & 63;
  if (tid < 8) cnt[tid] = 0;
  __syncthreads();
  for (int n0 = 0; n0 < N; n0 += nt) {
    int n = n0 + tid;
    int a = (n < N) ? attrs[n] : -1;
#pragma unroll
    for (int b = 0; b < 7; b++) {
      unsigned long long m = __ballot(a == b);
      if (m && lane == 0) atomicAdd(&cnt[b], __popcll(m));
    }
  }
  __syncthreads();
  if (tid == 0) {
    int o = 0;
    for (int a = 0; a < 7; a++) { off[a] = o; cur[a] = o; o += ((cnt[a] + 127) >> 7) << 7; }
    off[7] = o;
  }
  __syncthreads();
  int Mpad = maxTiles << 7;
  for (int i = tid; i < Mpad; i += nt) perm[i] = -1;
  for (int t = tid; t < maxTiles; t += nt) {
    int row = t << 7;
    int a = 0;
    for (int b = 1; b < 7; b++) if (row >= off[b]) a = b;
    tattr[t] = (row < off[7]) ? a : 0;
  }
  __syncthreads();
  for (int n0 = 0; n0 < N; n0 += nt) {
    int n = n0 + tid;
    int a = (n < N) ? attrs[n] : -1;
#pragma unroll
    for (int b = 0; b < 7; b++) {
      unsigned long long m = __ballot(a == b);
      if (m) {
        int lead = __ffsll(m) - 1;
        int base = 0;
        if (lane == lead) base = atomicAdd(&cur[b], __popcll(m));
        base = __shfl(base, lead, 64);
        if (a == b) {
          int pre = __popcll(m & ((1ull << lane) - 1ull));
          perm[base + pre] = n;
        }
      }
    }
  }
}

// x_sorted (Mpad,1024) bf16: plain=[f0,f1] or prod=[f0*f1, f1*f2]
__global__ void k_build_x(const int* __restrict__ perm, const int* __restrict__ attrs,
                          const u16* __restrict__ feats, u16* __restrict__ x) {
  int row = blockIdx.x;
  int c0 = threadIdx.x << 2;
  u16* xr = x + (size_t)row * 1024;
  int n = perm[row];
  if (n < 0) { ushort4 z = {0, 0, 0, 0}; *(ushort4*)&xr[c0] = z; return; }
  int attr = attrs[n];
  bool dist = (attr == 5) || (attr == 6);
  const u16* fb = feats + (size_t)(n * 3) * 512;
  ushort4 o;
  if (c0 < 512) {
    ushort4 a = *(const ushort4*)&fb[c0];            // f0
    if (dist) {
      ushort4 b = *(const ushort4*)&fb[512 + c0];    // f1
      o.x = f2b(b2f(a.x) * b2f(b.x)); o.y = f2b(b2f(a.y) * b2f(b.y));
      o.z = f2b(b2f(a.z) * b2f(b.z)); o.w = f2b(b2f(a.w) * b2f(b.w));
    } else o = a;
  } else {
    int c = c0 - 512;
    ushort4 a = *(const ushort4*)&fb[512 + c];       // f1
    if (dist) {
      ushort4 b = *(const ushort4*)&fb[1024 + c];    // f2
      o.x = f2b(b2f(a.x) * b2f(b.x)); o.y = f2b(b2f(a.y) * b2f(b.y));
      o.z = f2b(b2f(a.z) * b2f(b.z)); o.w = f2b(b2f(a.w) * b2f(b.w));
    } else o = a;
  }
  *(ushort4*)&xr[c0] = o;
}

// Layer-1 GEMM fused with fp32->bf16 A conversion:
// C(M1,512) = relu(bf16(img rows s=0..2) * Wt^T + bcnn).
// A staged reg-side (global fp32 -> pack -> ds_write_b128, linear LDS, same
// layout gload_lds would produce); B staged via global_load_lds. 128x128, BK=64.
__global__ __launch_bounds__(256) void k_gemm_img(
    const float* __restrict__ img, const u16* __restrict__ Bt,
    const float* __restrict__ bias, u16* __restrict__ C, int K) {
  __shared__ u16 sA[128 * 64];
  __shared__ u16 sB[128 * 64];
  int tid = threadIdx.x;
  int bm = blockIdx.x, bn = blockIdx.y;
  const u16* Bb = Bt + (size_t)bn * 128 * K;
  int lane = tid & 63, wave = tid >> 6;
  int wm = (wave >> 1) * 64, wn = (wave & 1) * 64;
  int lr = lane & 15, lq = lane >> 4;
  floatx4 acc[4][4];
#pragma unroll
  for (int i = 0; i < 4; i++)
#pragma unroll
    for (int j = 0; j < 4; j++) acc[i][j] = floatx4{0.f, 0.f, 0.f, 0.f};
  int r = tid >> 3;            // 0..31
  int c8 = (tid & 7) << 3;     // 0..56
  // per-thread A row pointers: tile row -> img row (n*8+s), s=0..2
  const float* aptr[4];
#pragma unroll
  for (int i = 0; i < 4; i++) {
    int arow = bm * 128 + i * 32 + r;
    int n3 = arow / 3, s = arow - n3 * 3;
    aptr[i] = img + (size_t)(n3 * 8 + s) * 3200 + c8;
  }
  int iters = K >> 6;
  for (int kk = 0; kk < iters; kk++) {
    int k0 = kk << 6;
    const u16* Bbk = Bb + k0 + c8;
#pragma unroll
    for (int i = 0; i < 4; i++)
      gload_lds16(Bbk + (size_t)(r + i * 32) * K, &sB[(size_t)(tid + i * 256) << 3]);
    float4 va[8];
#pragma unroll
    for (int i = 0; i < 4; i++) {
      va[2 * i]     = *(const float4*)(aptr[i] + k0);
      va[2 * i + 1] = *(const float4*)(aptr[i] + k0 + 4);
    }
#pragma unroll
    for (int i = 0; i < 4; i++) {
      uint4 p;
      p.x = pk2(va[2 * i].x,     va[2 * i].y);
      p.y = pk2(va[2 * i].z,     va[2 * i].w);
      p.z = pk2(va[2 * i + 1].x, va[2 * i + 1].y);
      p.w = pk2(va[2 * i + 1].z, va[2 * i + 1].w);
      *(uint4*)&sA[(size_t)(tid + i * 256) << 3] = p;   // linear: row (i*32+r), col c8
    }
    __syncthreads();
#pragma unroll
    for (int ks = 0; ks < 2; ks++) {
      int kb = (ks << 5) + (lq << 3);
      bf16x8 af[4], bg[4];
#pragma unroll
      for (int i = 0; i < 4; i++) {
        af[i] = *(const bf16x8*)&sA[(wm + i * 16 + lr) * 64 + kb];
        bg[i] = *(const bf16x8*)&sB[(wn + i * 16 + lr) * 64 + kb];
      }
#pragma unroll
      for (int i = 0; i < 4; i++)
#pragma unroll
        for (int j = 0; j < 4; j++)
          acc[i][j] = __builtin_amdgcn_mfma_f32_16x16x32_bf16(af[i], bg[j], acc[i][j], 0, 0, 0);
    }
    __syncthreads();
  }
  // epilogue: C/D layout col=lane&15, row=quad*4+reg (m89/m91-verified)
  int colBase = bn * 128 + wn + lr;
  int rowBase = bm * 128 + wm + lq * 4;
#pragma unroll
  for (int i = 0; i < 4; i++) {
#pragma unroll
    for (int j = 0; j < 4; j++) {
      int col = colBase + j * 16;
      float bv = bias[col];
#pragma unroll
      for (int r4 = 0; r4 < 4; r4++) {
        int row = rowBase + i * 16 + r4;
        float v = fmaxf(acc[i][j][r4] + bv, 0.f);
        C[(size_t)row * 512 + col] = f2b(v);
      }
    }
  }
}

// C(M,512) = relu(A(M,K) * Bt(512,K)^T + bias), bf16 out. 128x128 tile, BK=64.
// Grid: (bmTilesPadded, 4). bm on x so same-A blocks (ids bm + gridX*bn) land on
// the same XCD when gridX % 8 == 0 -> A-tile is 1-miss-3-hit in that XCD's L2.
__global__ __launch_bounds__(256) void k_gemm_bt(
    const u16* __restrict__ A, const u16* __restrict__ Bt,
    const float* __restrict__ bias, u16* __restrict__ C,
    int K, const int* __restrict__ tattr, int bStride, int biasStride, int mTiles) {
  __shared__ u16 sA[128 * 64];
  __shared__ u16 sB[128 * 64];
  int tid = threadIdx.x;
  int bm = blockIdx.x, bn = blockIdx.y;
  if (bm >= mTiles) return;   // uniform per block: safe w.r.t. barriers
  int attr = tattr ? tattr[bm] : 0;
  const u16* Ab = A + (size_t)bm * 128 * K;
  const u16* Bb = Bt + (size_t)attr * bStride + (size_t)bn * 128 * K;
  int lane = tid & 63, wave = tid >> 6;
  int wm = (wave >> 1) * 64, wn = (wave & 1) * 64;
  int lr = lane & 15, lq = lane >> 4;
  floatx4 acc[4][4];
#pragma unroll
  for (int i = 0; i < 4; i++)
#pragma unroll
    for (int j = 0; j < 4; j++) acc[i][j] = floatx4{0.f, 0.f, 0.f, 0.f};
  int r = tid >> 3;            // 0..31
  int c8 = (tid & 7) << 3;     // 0..56
  int iters = K >> 6;
  for (int kk = 0; kk < iters; kk++) {
    int k0 = kk << 6;
    const u16* Abk = Ab + k0 + c8;
    const u16* Bbk = Bb + k0 + c8;
#pragma unroll
    for (int i = 0; i < 4; i++) {
      gload_lds16(Abk + (size_t)(r + i * 32) * K, &sA[(size_t)(tid + i * 256) << 3]);
      gload_lds16(Bbk + (size_t)(r + i * 32) * K, &sB[(size_t)(tid + i * 256) << 3]);
    }
    __syncthreads();
#pragma unroll
    for (int ks = 0; ks < 2; ks++) {
      int kb = (ks << 5) + (lq << 3);
      bf16x8 af[4], bg[4];
#pragma unroll
      for (int i = 0; i < 4; i++) {
        af[i] = *(const bf16x8*)&sA[(wm + i * 16 + lr) * 64 + kb];
        bg[i] = *(const bf16x8*)&sB[(wn + i * 16 + lr) * 64 + kb];
      }
#pragma unroll
      for (int i = 0; i < 4; i++)
#pragma unroll
        for (int j = 0; j < 4; j++)
          acc[i][j] = __builtin_amdgcn_mfma_f32_16x16x32_bf16(af[i], bg[j], acc[i][j], 0, 0, 0);
    }
    __syncthreads();
  }
  // epilogue: C/D layout col=lane&15, row=quad*4+reg (m89/m91-verified)
  const float* br = bias + attr * biasStride;
  int colBase = bn * 128 + wn + lr;
  int rowBase = bm * 128 + wm + lq * 4;
#pragma unroll
  for (int i = 0; i < 4; i++) {
#pragma unroll
    for (int j = 0; j < 4; j++) {
      int col = colBase + j * 16;
      float bv = br[col];
#pragma unroll
      for (int r4 = 0; r4 < 4; r4++) {
        int row = rowBase + i * 16 + r4;
        float v = fmaxf(acc[i][j][r4] + bv, 0.f);
        C[(size_t)row * 512 + col] = f2b(v);
      }
    }
  }
}

// scores[n,0:2] = h[row]·W2[attr] + b2[attr], fp32, scatter via perm
__global__ void k_layer3(const int* __restrict__ perm, const int* __restrict__ attrs,
                         const u16* __restrict__ h, const float* __restrict__ W2,
                         const float* __restrict__ b2, float* __restrict__ out) {
  int row = blockIdx.x * 4 + (threadIdx.x >> 6);
  int lane = threadIdx.x & 63;
  int n = perm[row];
  if (n < 0) return;
  int attr = attrs[n];
  const u16* hp = h + (size_t)row * 512 + lane * 8;
  uint4 hv = *(const uint4*)hp;
  float hf[8];
  hf[0] = b2f((u16)(hv.x & 0xFFFF)); hf[1] = b2f((u16)(hv.x >> 16));
  hf[2] = b2f((u16)(hv.y & 0xFFFF)); hf[3] = b2f((u16)(hv.y >> 16));
  hf[4] = b2f((u16)(hv.z & 0xFFFF)); hf[5] = b2f((u16)(hv.z >> 16));
  hf[6] = b2f((u16)(hv.w & 0xFFFF)); hf[7] = b2f((u16)(hv.w >> 16));
  const float* w = W2 + attr * 1024 + lane * 16;   // (f*2+a), f=lane*8..+7
  float a0 = 0.f, a1 = 0.f;
#pragma unroll
  for (int j = 0; j < 8; j++) { a0 += hf[j] * w[2 * j]; a1 += hf[j] * w[2 * j + 1]; }
#pragma unroll
  for (int m = 32; m; m >>= 1) { a0 += __shfl_xor(a0, m, 64); a1 += __shfl_xor(a1, m, 64); }
  if (lane == 0) {
    out[(size_t)n * 2 + 0] = a0 + b2[attr * 2 + 0];
    out[(size_t)n * 2 + 1] = a1 + b2[attr * 2 + 1];
  }
}

extern "C" void kernel_launch(void* const* d_in, const int* in_sizes, int n_in,
                              void* d_out, int out_size, void* d_ws, size_t ws_size,
                              hipStream_t stream) {
  const float* img   = (const float*)d_in[0];
  const int*   attrs = (const int*)d_in[1];
  const float* Wcnn  = (const float*)d_in[2];
  const float* bcnn  = (const float*)d_in[3];
  const float* W1    = (const float*)d_in[4];
  const float* b1    = (const float*)d_in[5];
  const float* W2    = (const float*)d_in[6];
  const float* b2    = (const float*)d_in[7];
  float* out = (float*)d_out;

  int N = in_sizes[1];          // 8192
  int M1 = N * 3;               // 24576 rows for layer-1 GEMM
  int mtiles1 = M1 / 128;       // 192 (multiple of 8 -> XCD-aligned swizzle)
  int maxTiles = N / 128 + 7;   // 71 (worst-case padded bucket tiles)
  int mtiles2p = (maxTiles + 7) & ~7;  // 72, pad so gridX % 8 == 0
  int Mpad = maxTiles * 128;    // 9088

  char* ws = (char*)d_ws;
  size_t off = 0;
  auto alloc = [&](size_t b) { char* p = ws + off; off += (b + 255) & ~(size_t)255; return p; };
  u16* Wt    = (u16*)alloc((size_t)512 * 3200 * 2);      // 3.3 MB  (W_cnn^T)
  u16* W1t   = (u16*)alloc((size_t)7 * 512 * 1024 * 2);  // 7.3 MB  (W1^T per attr)
  u16* feats = (u16*)alloc((size_t)M1 * 512 * 2);        // 25 MB
  u16* xs    = (u16*)alloc((size_t)Mpad * 1024 * 2);     // 18.6 MB
  u16* hs    = (u16*)alloc((size_t)Mpad * 512 * 2);      // 9.3 MB
  int* perm  = (int*)alloc((size_t)Mpad * 4);
  int* tattr = (int*)alloc((size_t)maxTiles * 4);

  hipLaunchKernelGGL(k_transpose_tile, dim3(3200 / 32, 512 / 32, 1), dim3(256), 0, stream,
                     Wcnn, Wt, 3200, 512);
  hipLaunchKernelGGL(k_transpose_tile, dim3(1024 / 32, 512 / 32, 7), dim3(256), 0, stream,
                     W1, W1t, 1024, 512);
  hipLaunchKernelGGL(k_bucket, dim3(1), dim3(1024), 0, stream, attrs, N, maxTiles, perm, tattr);
  hipLaunchKernelGGL(k_gemm_img, dim3(mtiles1, 4), dim3(256), 0, stream,
                     img, Wt, bcnn, feats, 3200);
  hipLaunchKernelGGL(k_build_x, dim3(Mpad), dim3(256), 0, stream, perm, attrs, feats, xs);
  hipLaunchKernelGGL(k_gemm_bt, dim3(mtiles2p, 4), dim3(256), 0, stream,
                     xs, W1t, b1, hs, 1024, tattr, 512 * 1024, 512, maxTiles);
  hipLaunchKernelGGL(k_layer3, dim3(Mpad / 4), dim3(256), 0, stream, perm, attrs, hs, W2, b2, out);
}

// Round 5
// 1200.115 us; speedup vs baseline: 1.0344x; 1.0080x over previous
//
#include <hip/hip_runtime.h>
#include <stdint.h>

typedef unsigned short u16;
typedef short bf16x8 __attribute__((ext_vector_type(8)));
typedef float floatx4 __attribute__((ext_vector_type(4)));

__device__ __forceinline__ u16 f2b(float f) {
  union { float f; unsigned u; } v; v.f = f;
  return (u16)((v.u + 0x7FFFu + ((v.u >> 16) & 1u)) >> 16);
}
__device__ __forceinline__ float b2f(u16 u) {
  union { float f; unsigned u; } v; v.u = ((unsigned)u) << 16; return v.f;
}
// pack two fp32 -> one u32 holding (bf16(lo) | bf16(hi)<<16), RNE
__device__ __forceinline__ unsigned pk2(float lo, float hi) {
  return (unsigned)f2b(lo) | ((unsigned)f2b(hi) << 16);
}
__device__ __forceinline__ void gload_lds16(const void* g, void* l) {
  __builtin_amdgcn_global_load_lds((const __attribute__((address_space(1))) void*)g,
                                   (__attribute__((address_space(3))) void*)l, 16, 0, 0);
}

// LDS-tiled transpose: in (batch,R,C) fp32 -> out (batch,C,R) bf16. 32x32 tiles.
__global__ void k_transpose_tile(const float* __restrict__ in, u16* __restrict__ out,
                                 int R, int C) {
  __shared__ float t[32][33];
  int a = blockIdx.z;
  const float* src = in + (size_t)a * R * C;
  u16* dst = out + (size_t)a * R * C;
  int rb = blockIdx.x << 5, cb = blockIdx.y << 5;
  int tx = threadIdx.x & 31, ty = threadIdx.x >> 5;   // 32 x 8
#pragma unroll
  for (int i = 0; i < 32; i += 8)
    t[ty + i][tx] = src[(size_t)(rb + ty + i) * C + cb + tx];
  __syncthreads();
#pragma unroll
  for (int i = 0; i < 32; i += 8)
    dst[(size_t)(cb + ty + i) * R + rb + tx] = f2b(t[tx][ty + i]);
}

// bucket samples by attr; buckets padded to multiple of 128 rows.
// Wave-aggregated counting/scatter: uniform-address atomics only (G12).
// Also zeroes the 4KB zbuf scratch used by k_gemm_x for padding rows,
// and marks pure-padding tiles with tattr = -1.
__global__ void k_bucket(const int* __restrict__ attrs, int N, int maxTiles,
                         int* __restrict__ perm, int* __restrict__ tattr,
                         u16* __restrict__ zbuf) {
  __shared__ int cnt[8], off[8], cur[8];
  int tid = threadIdx.x;
  int nt = blockDim.x;
  int lane = tid & 63;
  if (tid < 8) cnt[tid] = 0;
  for (int i = tid; i < 2048; i += nt) zbuf[i] = 0;
  __syncthreads();
  for (int n0 = 0; n0 < N; n0 += nt) {
    int n = n0 + tid;
    int a = (n < N) ? attrs[n] : -1;
#pragma unroll
    for (int b = 0; b < 7; b++) {
      unsigned long long m = __ballot(a == b);
      if (m && lane == 0) atomicAdd(&cnt[b], __popcll(m));
    }
  }
  __syncthreads();
  if (tid == 0) {
    int o = 0;
    for (int a = 0; a < 7; a++) { off[a] = o; cur[a] = o; o += ((cnt[a] + 127) >> 7) << 7; }
    off[7] = o;
  }
  __syncthreads();
  int Mpad = maxTiles << 7;
  for (int i = tid; i < Mpad; i += nt) perm[i] = -1;
  for (int t = tid; t < maxTiles; t += nt) {
    int row = t << 7;
    int a = 0;
    for (int b = 1; b < 7; b++) if (row >= off[b]) a = b;
    tattr[t] = (row < off[7]) ? a : -1;   // -1: tile is pure padding, skip
  }
  __syncthreads();
  for (int n0 = 0; n0 < N; n0 += nt) {
    int n = n0 + tid;
    int a = (n < N) ? attrs[n] : -1;
#pragma unroll
    for (int b = 0; b < 7; b++) {
      unsigned long long m = __ballot(a == b);
      if (m) {
        int lead = __ffsll(m) - 1;
        int base = 0;
        if (lane == lead) base = atomicAdd(&cur[b], __popcll(m));
        base = __shfl(base, lead, 64);
        if (a == b) {
          int pre = __popcll(m & ((1ull << lane) - 1ull));
          perm[base + pre] = n;
        }
      }
    }
  }
}

// Layer-1 GEMM fused with fp32->bf16 A conversion:
// C(M1,512) = relu(bf16(img rows s=0..2) * Wt^T + bcnn).
// A staged reg-side (global fp32 -> pack -> ds_write_b128, linear LDS, same
// layout gload_lds would produce); B staged via global_load_lds. 128x128, BK=64.
__global__ __launch_bounds__(256) void k_gemm_img(
    const float* __restrict__ img, const u16* __restrict__ Bt,
    const float* __restrict__ bias, u16* __restrict__ C, int K) {
  __shared__ u16 sA[128 * 64];
  __shared__ u16 sB[128 * 64];
  int tid = threadIdx.x;
  int bm = blockIdx.x, bn = blockIdx.y;
  const u16* Bb = Bt + (size_t)bn * 128 * K;
  int lane = tid & 63, wave = tid >> 6;
  int wm = (wave >> 1) * 64, wn = (wave & 1) * 64;
  int lr = lane & 15, lq = lane >> 4;
  floatx4 acc[4][4];
#pragma unroll
  for (int i = 0; i < 4; i++)
#pragma unroll
    for (int j = 0; j < 4; j++) acc[i][j] = floatx4{0.f, 0.f, 0.f, 0.f};
  int r = tid >> 3;            // 0..31
  int c8 = (tid & 7) << 3;     // 0..56
  // per-thread A row pointers: tile row -> img row (n*8+s), s=0..2
  const float* aptr[4];
#pragma unroll
  for (int i = 0; i < 4; i++) {
    int arow = bm * 128 + i * 32 + r;
    int n3 = arow / 3, s = arow - n3 * 3;
    aptr[i] = img + (size_t)(n3 * 8 + s) * 3200 + c8;
  }
  int iters = K >> 6;
  for (int kk = 0; kk < iters; kk++) {
    int k0 = kk << 6;
    const u16* Bbk = Bb + k0 + c8;
#pragma unroll
    for (int i = 0; i < 4; i++)
      gload_lds16(Bbk + (size_t)(r + i * 32) * K, &sB[(size_t)(tid + i * 256) << 3]);
    float4 va[8];
#pragma unroll
    for (int i = 0; i < 4; i++) {
      va[2 * i]     = *(const float4*)(aptr[i] + k0);
      va[2 * i + 1] = *(const float4*)(aptr[i] + k0 + 4);
    }
#pragma unroll
    for (int i = 0; i < 4; i++) {
      uint4 p;
      p.x = pk2(va[2 * i].x,     va[2 * i].y);
      p.y = pk2(va[2 * i].z,     va[2 * i].w);
      p.z = pk2(va[2 * i + 1].x, va[2 * i + 1].y);
      p.w = pk2(va[2 * i + 1].z, va[2 * i + 1].w);
      *(uint4*)&sA[(size_t)(tid + i * 256) << 3] = p;   // linear: row (i*32+r), col c8
    }
    __syncthreads();
#pragma unroll
    for (int ks = 0; ks < 2; ks++) {
      int kb = (ks << 5) + (lq << 3);
      bf16x8 af[4], bg[4];
#pragma unroll
      for (int i = 0; i < 4; i++) {
        af[i] = *(const bf16x8*)&sA[(wm + i * 16 + lr) * 64 + kb];
        bg[i] = *(const bf16x8*)&sB[(wn + i * 16 + lr) * 64 + kb];
      }
#pragma unroll
      for (int i = 0; i < 4; i++)
#pragma unroll
        for (int j = 0; j < 4; j++)
          acc[i][j] = __builtin_amdgcn_mfma_f32_16x16x32_bf16(af[i], bg[j], acc[i][j], 0, 0, 0);
    }
    __syncthreads();
  }
  // epilogue: C/D layout col=lane&15, row=quad*4+reg (m89/m91-verified)
  int colBase = bn * 128 + wn + lr;
  int rowBase = bm * 128 + wm + lq * 4;
#pragma unroll
  for (int i = 0; i < 4; i++) {
#pragma unroll
    for (int j = 0; j < 4; j++) {
      int col = colBase + j * 16;
      float bv = bias[col];
#pragma unroll
      for (int r4 = 0; r4 < 4; r4++) {
        int row = rowBase + i * 16 + r4;
        float v = fmaxf(acc[i][j][r4] + bv, 0.f);
        C[(size_t)row * 512 + col] = f2b(v);
      }
    }
  }
}

// Layer-2 GEMM fused with x-construction (k_build_x eliminated):
// hs(row, 0:512) = relu(x(row,:) * W1t[attr]^T + b1[attr]),
// where x(row, k) = plain: feats[n*3*512 + k]            (f0|f1 concat, linear!)
//                   dist:  feats[n*3*512 + k] * feats[n*3*512 + k + 512]
// attr (hence dist) is uniform per bucket tile. Padding rows read a zeroed
// 4KB scratch. Pure-padding tiles (tattr=-1) skip entirely (uniform return).
__global__ __launch_bounds__(256) void k_gemm_x(
    const u16* __restrict__ feats, const int* __restrict__ perm,
    const u16* __restrict__ zbuf, const u16* __restrict__ W1t,
    const float* __restrict__ b1, u16* __restrict__ C,
    const int* __restrict__ tattr, int mTiles) {
  __shared__ u16 sA[128 * 64];
  __shared__ u16 sB[128 * 64];
  int tid = threadIdx.x;
  int bm = blockIdx.x, bn = blockIdx.y;
  if (bm >= mTiles) return;            // uniform per block
  int attr = tattr[bm];
  if (attr < 0) return;                // pure-padding tile (uniform)
  bool dist = (attr == 5) || (attr == 6);   // block-uniform branch
  const u16* Bb = W1t + (size_t)attr * (512 * 1024) + (size_t)bn * 128 * 1024;
  int lane = tid & 63, wave = tid >> 6;
  int wm = (wave >> 1) * 64, wn = (wave & 1) * 64;
  int lr = lane & 15, lq = lane >> 4;
  floatx4 acc[4][4];
#pragma unroll
  for (int i = 0; i < 4; i++)
#pragma unroll
    for (int j = 0; j < 4; j++) acc[i][j] = floatx4{0.f, 0.f, 0.f, 0.f};
  int r = tid >> 3;            // 0..31
  int c8 = (tid & 7) << 3;     // 0..56
  const u16* base[4];
#pragma unroll
  for (int i = 0; i < 4; i++) {
    int n = perm[bm * 128 + i * 32 + r];
    base[i] = (n < 0) ? zbuf : feats + (size_t)n * 3 * 512;
  }
  for (int kk = 0; kk < 16; kk++) {
    int k0 = kk << 6;
#pragma unroll
    for (int i = 0; i < 4; i++)
      gload_lds16(Bb + (size_t)(r + i * 32) * 1024 + k0 + c8,
                  &sB[(size_t)(tid + i * 256) << 3]);
    if (!dist) {
#pragma unroll
      for (int i = 0; i < 4; i++)
        gload_lds16(base[i] + k0 + c8, &sA[(size_t)(tid + i * 256) << 3]);
    } else {
#pragma unroll
      for (int i = 0; i < 4; i++) {
        const u16* s = base[i] + k0 + c8;
        ushort4 a0 = *(const ushort4*)s;
        ushort4 a1 = *(const ushort4*)(s + 4);
        ushort4 m0 = *(const ushort4*)(s + 512);
        ushort4 m1 = *(const ushort4*)(s + 516);
        uint4 p;
        p.x = pk2(b2f(a0.x) * b2f(m0.x), b2f(a0.y) * b2f(m0.y));
        p.y = pk2(b2f(a0.z) * b2f(m0.z), b2f(a0.w) * b2f(m0.w));
        p.z = pk2(b2f(a1.x) * b2f(m1.x), b2f(a1.y) * b2f(m1.y));
        p.w = pk2(b2f(a1.z) * b2f(m1.z), b2f(a1.w) * b2f(m1.w));
        *(uint4*)&sA[(size_t)(tid + i * 256) << 3] = p;
      }
    }
    __syncthreads();
#pragma unroll
    for (int ks = 0; ks < 2; ks++) {
      int kb = (ks << 5) + (lq << 3);
      bf16x8 af[4], bg[4];
#pragma unroll
      for (int i = 0; i < 4; i++) {
        af[i] = *(const bf16x8*)&sA[(wm + i * 16 + lr) * 64 + kb];
        bg[i] = *(const bf16x8*)&sB[(wn + i * 16 + lr) * 64 + kb];
      }
#pragma unroll
      for (int i = 0; i < 4; i++)
#pragma unroll
        for (int j = 0; j < 4; j++)
          acc[i][j] = __builtin_amdgcn_mfma_f32_16x16x32_bf16(af[i], bg[j], acc[i][j], 0, 0, 0);
    }
    __syncthreads();
  }
  // epilogue: C/D layout col=lane&15, row=quad*4+reg (m89/m91-verified)
  const float* br = b1 + attr * 512;
  int colBase = bn * 128 + wn + lr;
  int rowBase = bm * 128 + wm + lq * 4;
#pragma unroll
  for (int i = 0; i < 4; i++) {
#pragma unroll
    for (int j = 0; j < 4; j++) {
      int col = colBase + j * 16;
      float bv = br[col];
#pragma unroll
      for (int r4 = 0; r4 < 4; r4++) {
        int row = rowBase + i * 16 + r4;
        float v = fmaxf(acc[i][j][r4] + bv, 0.f);
        C[(size_t)row * 512 + col] = f2b(v);
      }
    }
  }
}

// scores[n,0:2] = h[row]·W2[attr] + b2[attr], fp32, scatter via perm
__global__ void k_layer3(const int* __restrict__ perm, const int* __restrict__ attrs,
                         const u16* __restrict__ h, const float* __restrict__ W2,
                         const float* __restrict__ b2, float* __restrict__ out) {
  int row = blockIdx.x * 4 + (threadIdx.x >> 6);
  int lane = threadIdx.x & 63;
  int n = perm[row];
  if (n < 0) return;
  int attr = attrs[n];
  const u16* hp = h + (size_t)row * 512 + lane * 8;
  uint4 hv = *(const uint4*)hp;
  float hf[8];
  hf[0] = b2f((u16)(hv.x & 0xFFFF)); hf[1] = b2f((u16)(hv.x >> 16));
  hf[2] = b2f((u16)(hv.y & 0xFFFF)); hf[3] = b2f((u16)(hv.y >> 16));
  hf[4] = b2f((u16)(hv.z & 0xFFFF)); hf[5] = b2f((u16)(hv.z >> 16));
  hf[6] = b2f((u16)(hv.w & 0xFFFF)); hf[7] = b2f((u16)(hv.w >> 16));
  const float* w = W2 + attr * 1024 + lane * 16;   // (f*2+a), f=lane*8..+7
  float a0 = 0.f, a1 = 0.f;
#pragma unroll
  for (int j = 0; j < 8; j++) { a0 += hf[j] * w[2 * j]; a1 += hf[j] * w[2 * j + 1]; }
#pragma unroll
  for (int m = 32; m; m >>= 1) { a0 += __shfl_xor(a0, m, 64); a1 += __shfl_xor(a1, m, 64); }
  if (lane == 0) {
    out[(size_t)n * 2 + 0] = a0 + b2[attr * 2 + 0];
    out[(size_t)n * 2 + 1] = a1 + b2[attr * 2 + 1];
  }
}

extern "C" void kernel_launch(void* const* d_in, const int* in_sizes, int n_in,
                              void* d_out, int out_size, void* d_ws, size_t ws_size,
                              hipStream_t stream) {
  const float* img   = (const float*)d_in[0];
  const int*   attrs = (const int*)d_in[1];
  const float* Wcnn  = (const float*)d_in[2];
  const float* bcnn  = (const float*)d_in[3];
  const float* W1    = (const float*)d_in[4];
  const float* b1    = (const float*)d_in[5];
  const float* W2    = (const float*)d_in[6];
  const float* b2    = (const float*)d_in[7];
  float* out = (float*)d_out;

  int N = in_sizes[1];          // 8192
  int M1 = N * 3;               // 24576 rows for layer-1 GEMM
  int mtiles1 = M1 / 128;       // 192 (multiple of 8 -> XCD-aligned swizzle)
  int maxTiles = N / 128 + 7;   // 71 (worst-case padded bucket tiles)
  int mtiles2p = (maxTiles + 7) & ~7;  // 72, pad so gridX % 8 == 0
  int Mpad = maxTiles * 128;    // 9088

  char* ws = (char*)d_ws;
  size_t off = 0;
  auto alloc = [&](size_t b) { char* p = ws + off; off += (b + 255) & ~(size_t)255; return p; };
  u16* Wt    = (u16*)alloc((size_t)512 * 3200 * 2);      // 3.3 MB  (W_cnn^T)
  u16* W1t   = (u16*)alloc((size_t)7 * 512 * 1024 * 2);  // 7.3 MB  (W1^T per attr)
  u16* feats = (u16*)alloc((size_t)M1 * 512 * 2);        // 25 MB
  u16* hs    = (u16*)alloc((size_t)Mpad * 512 * 2);      // 9.3 MB
  int* perm  = (int*)alloc((size_t)Mpad * 4);
  int* tattr = (int*)alloc((size_t)maxTiles * 4);
  u16* zbuf  = (u16*)alloc((size_t)2048 * 2);            // 4 KB zero scratch

  hipLaunchKernelGGL(k_transpose_tile, dim3(3200 / 32, 512 / 32, 1), dim3(256), 0, stream,
                     Wcnn, Wt, 3200, 512);
  hipLaunchKernelGGL(k_transpose_tile, dim3(1024 / 32, 512 / 32, 7), dim3(256), 0, stream,
                     W1, W1t, 1024, 512);
  hipLaunchKernelGGL(k_bucket, dim3(1), dim3(1024), 0, stream, attrs, N, maxTiles, perm, tattr, zbuf);
  hipLaunchKernelGGL(k_gemm_img, dim3(mtiles1, 4), dim3(256), 0, stream,
                     img, Wt, bcnn, feats, 3200);
  hipLaunchKernelGGL(k_gemm_x, dim3(mtiles2p, 4), dim3(256), 0, stream,
                     feats, perm, zbuf, W1t, b1, hs, tattr, maxTiles);
  hipLaunchKernelGGL(k_layer3, dim3(Mpad / 4), dim3(256), 0, stream, perm, attrs, hs, W2, b2, out);
}

// Round 6
// 1181.108 us; speedup vs baseline: 1.0510x; 1.0161x over previous
//
#include <hip/hip_runtime.h>
#include <stdint.h>

typedef unsigned short u16;
typedef short bf16x8 __attribute__((ext_vector_type(8)));
typedef float floatx4 __attribute__((ext_vector_type(4)));

__device__ __forceinline__ u16 f2b(float f) {
  union { float f; unsigned u; } v; v.f = f;
  return (u16)((v.u + 0x7FFFu + ((v.u >> 16) & 1u)) >> 16);
}
__device__ __forceinline__ float b2f(u16 u) {
  union { float f; unsigned u; } v; v.u = ((unsigned)u) << 16; return v.f;
}
// pack two fp32 -> one u32 holding (bf16(lo) | bf16(hi)<<16), RNE
__device__ __forceinline__ unsigned pk2(float lo, float hi) {
  return (unsigned)f2b(lo) | ((unsigned)f2b(hi) << 16);
}
__device__ __forceinline__ void gload_lds16(const void* g, void* l) {
  __builtin_amdgcn_global_load_lds((const __attribute__((address_space(1))) void*)g,
                                   (__attribute__((address_space(3))) void*)l, 16, 0, 0);
}

// LDS-tiled transpose: in (batch,R,C) fp32 -> out (batch,C,R) bf16. 32x32 tiles.
__global__ void k_transpose_tile(const float* __restrict__ in, u16* __restrict__ out,
                                 int R, int C) {
  __shared__ float t[32][33];
  int a = blockIdx.z;
  const float* src = in + (size_t)a * R * C;
  u16* dst = out + (size_t)a * R * C;
  int rb = blockIdx.x << 5, cb = blockIdx.y << 5;
  int tx = threadIdx.x & 31, ty = threadIdx.x >> 5;   // 32 x 8
#pragma unroll
  for (int i = 0; i < 32; i += 8)
    t[ty + i][tx] = src[(size_t)(rb + ty + i) * C + cb + tx];
  __syncthreads();
#pragma unroll
  for (int i = 0; i < 32; i += 8)
    dst[(size_t)(cb + ty + i) * R + rb + tx] = f2b(t[tx][ty + i]);
}

// bucket samples by attr; buckets padded to multiple of 128 rows.
// Wave-aggregated counting/scatter: uniform-address atomics only (G12).
// Also zeroes the 4KB zbuf scratch used by k_gemm_x for padding rows,
// and marks pure-padding tiles with tattr = -1.
__global__ void k_bucket(const int* __restrict__ attrs, int N, int maxTiles,
                         int* __restrict__ perm, int* __restrict__ tattr,
                         u16* __restrict__ zbuf) {
  __shared__ int cnt[8], off[8], cur[8];
  int tid = threadIdx.x;
  int nt = blockDim.x;
  int lane = tid & 63;
  if (tid < 8) cnt[tid] = 0;
  for (int i = tid; i < 2048; i += nt) zbuf[i] = 0;
  __syncthreads();
  for (int n0 = 0; n0 < N; n0 += nt) {
    int n = n0 + tid;
    int a = (n < N) ? attrs[n] : -1;
#pragma unroll
    for (int b = 0; b < 7; b++) {
      unsigned long long m = __ballot(a == b);
      if (m && lane == 0) atomicAdd(&cnt[b], __popcll(m));
    }
  }
  __syncthreads();
  if (tid == 0) {
    int o = 0;
    for (int a = 0; a < 7; a++) { off[a] = o; cur[a] = o; o += ((cnt[a] + 127) >> 7) << 7; }
    off[7] = o;
  }
  __syncthreads();
  int Mpad = maxTiles << 7;
  for (int i = tid; i < Mpad; i += nt) perm[i] = -1;
  for (int t = tid; t < maxTiles; t += nt) {
    int row = t << 7;
    int a = 0;
    for (int b = 1; b < 7; b++) if (row >= off[b]) a = b;
    tattr[t] = (row < off[7]) ? a : -1;   // -1: tile is pure padding, skip
  }
  __syncthreads();
  for (int n0 = 0; n0 < N; n0 += nt) {
    int n = n0 + tid;
    int a = (n < N) ? attrs[n] : -1;
#pragma unroll
    for (int b = 0; b < 7; b++) {
      unsigned long long m = __ballot(a == b);
      if (m) {
        int lead = __ffsll(m) - 1;
        int base = 0;
        if (lane == lead) base = atomicAdd(&cur[b], __popcll(m));
        base = __shfl(base, lead, 64);
        if (a == b) {
          int pre = __popcll(m & ((1ull << lane) - 1ull));
          perm[base + pre] = n;
        }
      }
    }
  }
}

// Layer-1 GEMM fused with fp32->bf16 A conversion, T14 async-split staging:
// C(M1,512) = relu(bf16(img rows s=0..2) * Wt^T + bcnn).
// A: fp32 global->reg loads issued during PREVIOUS tile's MFMA phase; pack+
//    ds_write at top of iter hits resident regs (no wait). B: double-buffered
//    LDS, gload_lds for tile kk+1 issued during MFMA(kk) -> latency hidden.
// Barriers: sync1 orders {sA write, B(kk) arrival} before MFMA; sync2 orders
// MFMA reads before next sA write, drains prefetches under MFMA cover.
__global__ __launch_bounds__(256) void k_gemm_img(
    const float* __restrict__ img, const u16* __restrict__ Bt,
    const float* __restrict__ bias, u16* __restrict__ C, int K) {
  __shared__ u16 sA[128 * 64];
  __shared__ u16 sB[2][128 * 64];
  int tid = threadIdx.x;
  int bm = blockIdx.x, bn = blockIdx.y;
  const u16* Bb = Bt + (size_t)bn * 128 * K;
  int lane = tid & 63, wave = tid >> 6;
  int wm = (wave >> 1) * 64, wn = (wave & 1) * 64;
  int lr = lane & 15, lq = lane >> 4;
  floatx4 acc[4][4];
#pragma unroll
  for (int i = 0; i < 4; i++)
#pragma unroll
    for (int j = 0; j < 4; j++) acc[i][j] = floatx4{0.f, 0.f, 0.f, 0.f};
  int r = tid >> 3;            // 0..31
  int c8 = (tid & 7) << 3;     // 0..56
  // per-thread A row pointers: tile row -> img row (n*8+s), s=0..2
  const float* aptr[4];
#pragma unroll
  for (int i = 0; i < 4; i++) {
    int arow = bm * 128 + i * 32 + r;
    int n3 = arow / 3, s = arow - n3 * 3;
    aptr[i] = img + (size_t)(n3 * 8 + s) * 3200 + c8;
  }
  int iters = K >> 6;
  // prologue: stage B(0) into sB[0], load A(0) into regs
#pragma unroll
  for (int i = 0; i < 4; i++)
    gload_lds16(Bb + (size_t)(r + i * 32) * K + c8, &sB[0][(size_t)(tid + i * 256) << 3]);
  float4 va[8];
#pragma unroll
  for (int i = 0; i < 4; i++) {
    va[2 * i]     = *(const float4*)(aptr[i]);
    va[2 * i + 1] = *(const float4*)(aptr[i] + 4);
  }
  for (int kk = 0; kk < iters; kk++) {
    int cur = kk & 1;
    // pack resident A regs -> sA (linear layout: row (i*32+r), col c8)
#pragma unroll
    for (int i = 0; i < 4; i++) {
      uint4 p;
      p.x = pk2(va[2 * i].x,     va[2 * i].y);
      p.y = pk2(va[2 * i].z,     va[2 * i].w);
      p.z = pk2(va[2 * i + 1].x, va[2 * i + 1].y);
      p.w = pk2(va[2 * i + 1].z, va[2 * i + 1].w);
      *(uint4*)&sA[(size_t)(tid + i * 256) << 3] = p;
    }
    __syncthreads();   // sync1: sA visible, B(kk) drained (covered by MFMA(kk-1))
    // issue next tile's staging during this tile's MFMA phase
    if (kk + 1 < iters) {
      int k1 = (kk + 1) << 6;
      const u16* Bn = Bb + k1 + c8;
#pragma unroll
      for (int i = 0; i < 4; i++)
        gload_lds16(Bn + (size_t)(r + i * 32) * K, &sB[cur ^ 1][(size_t)(tid + i * 256) << 3]);
#pragma unroll
      for (int i = 0; i < 4; i++) {
        va[2 * i]     = *(const float4*)(aptr[i] + k1);
        va[2 * i + 1] = *(const float4*)(aptr[i] + k1 + 4);
      }
    }
#pragma unroll
    for (int ks = 0; ks < 2; ks++) {
      int kb = (ks << 5) + (lq << 3);
      bf16x8 af[4], bg[4];
#pragma unroll
      for (int i = 0; i < 4; i++) {
        af[i] = *(const bf16x8*)&sA[(wm + i * 16 + lr) * 64 + kb];
        bg[i] = *(const bf16x8*)&sB[cur][(wn + i * 16 + lr) * 64 + kb];
      }
#pragma unroll
      for (int i = 0; i < 4; i++)
#pragma unroll
        for (int j = 0; j < 4; j++)
          acc[i][j] = __builtin_amdgcn_mfma_f32_16x16x32_bf16(af[i], bg[j], acc[i][j], 0, 0, 0);
    }
    __syncthreads();   // sync2: MFMA reads done; drains prefetches under MFMA cover
  }
  // epilogue: C/D layout col=lane&15, row=quad*4+reg (m89/m91-verified)
  int colBase = bn * 128 + wn + lr;
  int rowBase = bm * 128 + wm + lq * 4;
#pragma unroll
  for (int i = 0; i < 4; i++) {
#pragma unroll
    for (int j = 0; j < 4; j++) {
      int col = colBase + j * 16;
      float bv = bias[col];
#pragma unroll
      for (int r4 = 0; r4 < 4; r4++) {
        int row = rowBase + i * 16 + r4;
        float v = fmaxf(acc[i][j][r4] + bv, 0.f);
        C[(size_t)row * 512 + col] = f2b(v);
      }
    }
  }
}

// Layer-2 GEMM fused with x-construction (k_build_x eliminated):
// hs(row, 0:512) = relu(x(row,:) * W1t[attr]^T + b1[attr]),
// where x(row, k) = plain: feats[n*3*512 + k]            (f0|f1 concat, linear!)
//                   dist:  feats[n*3*512 + k] * feats[n*3*512 + k + 512]
// attr (hence dist) is uniform per bucket tile. Padding rows read a zeroed
// 4KB scratch. Pure-padding tiles (tattr=-1) skip entirely (uniform return).
__global__ __launch_bounds__(256) void k_gemm_x(
    const u16* __restrict__ feats, const int* __restrict__ perm,
    const u16* __restrict__ zbuf, const u16* __restrict__ W1t,
    const float* __restrict__ b1, u16* __restrict__ C,
    const int* __restrict__ tattr, int mTiles) {
  __shared__ u16 sA[128 * 64];
  __shared__ u16 sB[128 * 64];
  int tid = threadIdx.x;
  int bm = blockIdx.x, bn = blockIdx.y;
  if (bm >= mTiles) return;            // uniform per block
  int attr = tattr[bm];
  if (attr < 0) return;                // pure-padding tile (uniform)
  bool dist = (attr == 5) || (attr == 6);   // block-uniform branch
  const u16* Bb = W1t + (size_t)attr * (512 * 1024) + (size_t)bn * 128 * 1024;
  int lane = tid & 63, wave = tid >> 6;
  int wm = (wave >> 1) * 64, wn = (wave & 1) * 64;
  int lr = lane & 15, lq = lane >> 4;
  floatx4 acc[4][4];
#pragma unroll
  for (int i = 0; i < 4; i++)
#pragma unroll
    for (int j = 0; j < 4; j++) acc[i][j] = floatx4{0.f, 0.f, 0.f, 0.f};
  int r = tid >> 3;            // 0..31
  int c8 = (tid & 7) << 3;     // 0..56
  const u16* base[4];
#pragma unroll
  for (int i = 0; i < 4; i++) {
    int n = perm[bm * 128 + i * 32 + r];
    base[i] = (n < 0) ? zbuf : feats + (size_t)n * 3 * 512;
  }
  for (int kk = 0; kk < 16; kk++) {
    int k0 = kk << 6;
#pragma unroll
    for (int i = 0; i < 4; i++)
      gload_lds16(Bb + (size_t)(r + i * 32) * 1024 + k0 + c8,
                  &sB[(size_t)(tid + i * 256) << 3]);
    if (!dist) {
#pragma unroll
      for (int i = 0; i < 4; i++)
        gload_lds16(base[i] + k0 + c8, &sA[(size_t)(tid + i * 256) << 3]);
    } else {
#pragma unroll
      for (int i = 0; i < 4; i++) {
        const u16* s = base[i] + k0 + c8;
        ushort4 a0 = *(const ushort4*)s;
        ushort4 a1 = *(const ushort4*)(s + 4);
        ushort4 m0 = *(const ushort4*)(s + 512);
        ushort4 m1 = *(const ushort4*)(s + 516);
        uint4 p;
        p.x = pk2(b2f(a0.x) * b2f(m0.x), b2f(a0.y) * b2f(m0.y));
        p.y = pk2(b2f(a0.z) * b2f(m0.z), b2f(a0.w) * b2f(m0.w));
        p.z = pk2(b2f(a1.x) * b2f(m1.x), b2f(a1.y) * b2f(m1.y));
        p.w = pk2(b2f(a1.z) * b2f(m1.z), b2f(a1.w) * b2f(m1.w));
        *(uint4*)&sA[(size_t)(tid + i * 256) << 3] = p;
      }
    }
    __syncthreads();
#pragma unroll
    for (int ks = 0; ks < 2; ks++) {
      int kb = (ks << 5) + (lq << 3);
      bf16x8 af[4], bg[4];
#pragma unroll
      for (int i = 0; i < 4; i++) {
        af[i] = *(const bf16x8*)&sA[(wm + i * 16 + lr) * 64 + kb];
        bg[i] = *(const bf16x8*)&sB[(wn + i * 16 + lr) * 64 + kb];
      }
#pragma unroll
      for (int i = 0; i < 4; i++)
#pragma unroll
        for (int j = 0; j < 4; j++)
          acc[i][j] = __builtin_amdgcn_mfma_f32_16x16x32_bf16(af[i], bg[j], acc[i][j], 0, 0, 0);
    }
    __syncthreads();
  }
  // epilogue: C/D layout col=lane&15, row=quad*4+reg (m89/m91-verified)
  const float* br = b1 + attr * 512;
  int colBase = bn * 128 + wn + lr;
  int rowBase = bm * 128 + wm + lq * 4;
#pragma unroll
  for (int i = 0; i < 4; i++) {
#pragma unroll
    for (int j = 0; j < 4; j++) {
      int col = colBase + j * 16;
      float bv = br[col];
#pragma unroll
      for (int r4 = 0; r4 < 4; r4++) {
        int row = rowBase + i * 16 + r4;
        float v = fmaxf(acc[i][j][r4] + bv, 0.f);
        C[(size_t)row * 512 + col] = f2b(v);
      }
    }
  }
}

// scores[n,0:2] = h[row]·W2[attr] + b2[attr], fp32, scatter via perm
__global__ void k_layer3(const int* __restrict__ perm, const int* __restrict__ attrs,
                         const u16* __restrict__ h, const float* __restrict__ W2,
                         const float* __restrict__ b2, float* __restrict__ out) {
  int row = blockIdx.x * 4 + (threadIdx.x >> 6);
  int lane = threadIdx.x & 63;
  int n = perm[row];
  if (n < 0) return;
  int attr = attrs[n];
  const u16* hp = h + (size_t)row * 512 + lane * 8;
  uint4 hv = *(const uint4*)hp;
  float hf[8];
  hf[0] = b2f((u16)(hv.x & 0xFFFF)); hf[1] = b2f((u16)(hv.x >> 16));
  hf[2] = b2f((u16)(hv.y & 0xFFFF)); hf[3] = b2f((u16)(hv.y >> 16));
  hf[4] = b2f((u16)(hv.z & 0xFFFF)); hf[5] = b2f((u16)(hv.z >> 16));
  hf[6] = b2f((u16)(hv.w & 0xFFFF)); hf[7] = b2f((u16)(hv.w >> 16));
  const float* w = W2 + attr * 1024 + lane * 16;   // (f*2+a), f=lane*8..+7
  float a0 = 0.f, a1 = 0.f;
#pragma unroll
  for (int j = 0; j < 8; j++) { a0 += hf[j] * w[2 * j]; a1 += hf[j] * w[2 * j + 1]; }
#pragma unroll
  for (int m = 32; m; m >>= 1) { a0 += __shfl_xor(a0, m, 64); a1 += __shfl_xor(a1, m, 64); }
  if (lane == 0) {
    out[(size_t)n * 2 + 0] = a0 + b2[attr * 2 + 0];
    out[(size_t)n * 2 + 1] = a1 + b2[attr * 2 + 1];
  }
}

extern "C" void kernel_launch(void* const* d_in, const int* in_sizes, int n_in,
                              void* d_out, int out_size, void* d_ws, size_t ws_size,
                              hipStream_t stream) {
  const float* img   = (const float*)d_in[0];
  const int*   attrs = (const int*)d_in[1];
  const float* Wcnn  = (const float*)d_in[2];
  const float* bcnn  = (const float*)d_in[3];
  const float* W1    = (const float*)d_in[4];
  const float* b1    = (const float*)d_in[5];
  const float* W2    = (const float*)d_in[6];
  const float* b2    = (const float*)d_in[7];
  float* out = (float*)d_out;

  int N = in_sizes[1];          // 8192
  int M1 = N * 3;               // 24576 rows for layer-1 GEMM
  int mtiles1 = M1 / 128;       // 192 (multiple of 8 -> XCD-aligned swizzle)
  int maxTiles = N / 128 + 7;   // 71 (worst-case padded bucket tiles)
  int mtiles2p = (maxTiles + 7) & ~7;  // 72, pad so gridX % 8 == 0
  int Mpad = maxTiles * 128;    // 9088

  char* ws = (char*)d_ws;
  size_t off = 0;
  auto alloc = [&](size_t b) { char* p = ws + off; off += (b + 255) & ~(size_t)255; return p; };
  u16* Wt    = (u16*)alloc((size_t)512 * 3200 * 2);      // 3.3 MB  (W_cnn^T)
  u16* W1t   = (u16*)alloc((size_t)7 * 512 * 1024 * 2);  // 7.3 MB  (W1^T per attr)
  u16* feats = (u16*)alloc((size_t)M1 * 512 * 2);        // 25 MB
  u16* hs    = (u16*)alloc((size_t)Mpad * 512 * 2);      // 9.3 MB
  int* perm  = (int*)alloc((size_t)Mpad * 4);
  int* tattr = (int*)alloc((size_t)maxTiles * 4);
  u16* zbuf  = (u16*)alloc((size_t)2048 * 2);            // 4 KB zero scratch

  hipLaunchKernelGGL(k_transpose_tile, dim3(3200 / 32, 512 / 32, 1), dim3(256), 0, stream,
                     Wcnn, Wt, 3200, 512);
  hipLaunchKernelGGL(k_transpose_tile, dim3(1024 / 32, 512 / 32, 7), dim3(256), 0, stream,
                     W1, W1t, 1024, 512);
  hipLaunchKernelGGL(k_bucket, dim3(1), dim3(1024), 0, stream, attrs, N, maxTiles, perm, tattr, zbuf);
  hipLaunchKernelGGL(k_gemm_img, dim3(mtiles1, 4), dim3(256), 0, stream,
                     img, Wt, bcnn, feats, 3200);
  hipLaunchKernelGGL(k_gemm_x, dim3(mtiles2p, 4), dim3(256), 0, stream,
                     feats, perm, zbuf, W1t, b1, hs, tattr, maxTiles);
  hipLaunchKernelGGL(k_layer3, dim3(Mpad / 4), dim3(256), 0, stream, perm, attrs, hs, W2, b2, out);
}